// Round 1
// baseline (3038.481 us; speedup 1.0000x reference)
//
#include <hip/hip_runtime.h>

// GCN 3-layer forward: N=100000 nodes, E=1600000 edges, D=64.
// Inputs (fp32 unless noted): x[N,64], edge_index[2,E] (int32 from harness),
// W1[64,64], b1[64], W2[64,64], b2[64], W3[64,1], b3[1]. Output: [N,1] fp32.

#define THREADS 256

// ---- degree / norm -------------------------------------------------------
__global__ __launch_bounds__(THREADS) void k_count_deg(
    const int* __restrict__ dst, float* __restrict__ deg, int E) {
  int e = blockIdx.x * blockDim.x + threadIdx.x;
  if (e < E) atomicAdd(&deg[dst[e]], 1.0f);
}

__global__ __launch_bounds__(THREADS) void k_make_dinv(
    float* __restrict__ deg_dinv, int n) {
  int i = blockIdx.x * blockDim.x + threadIdx.x;
  if (i < n) deg_dinv[i] = rsqrtf(deg_dinv[i] + 1.0f);
}

// ---- dense GEMM: C[n,64] = A[n,64] @ W[64,64] ----------------------------
// 256 threads/block, 16 rows/block. W staged in LDS (16 KB).
__global__ __launch_bounds__(THREADS) void k_gemm64(
    const float* __restrict__ A, const float* __restrict__ W,
    float* __restrict__ C, int n) {
  __shared__ float Ws[64][64];
  __shared__ float As[16][64];
  int t = threadIdx.x;
  const float4* W4 = (const float4*)W;
  float4* Ws4 = (float4*)&Ws[0][0];
#pragma unroll
  for (int i = 0; i < 4; i++) Ws4[t + i * 256] = W4[t + i * 256];

  int row0 = blockIdx.x * 16;
  const float4* A4 = (const float4*)(A + (size_t)row0 * 64);
  float4* As4 = (float4*)&As[0][0];
  if (row0 + 16 <= n) {
    As4[t] = A4[t];
  } else {
    int elem = t * 4;                 // float index within tile
    if (row0 * 64 + elem < n * 64) As4[t] = A4[t];
  }
  __syncthreads();

  int tx = t & 63, ty = t >> 6;       // tx: col, ty: 0..3
  float acc0 = 0.f, acc1 = 0.f, acc2 = 0.f, acc3 = 0.f;
#pragma unroll
  for (int k = 0; k < 64; k++) {
    float w = Ws[k][tx];
    acc0 = fmaf(As[ty][k],      w, acc0);
    acc1 = fmaf(As[ty + 4][k],  w, acc1);
    acc2 = fmaf(As[ty + 8][k],  w, acc2);
    acc3 = fmaf(As[ty + 12][k], w, acc3);
  }
  if (row0 + ty      < n) C[(size_t)(row0 + ty)      * 64 + tx] = acc0;
  if (row0 + ty + 4  < n) C[(size_t)(row0 + ty + 4)  * 64 + tx] = acc1;
  if (row0 + ty + 8  < n) C[(size_t)(row0 + ty + 8)  * 64 + tx] = acc2;
  if (row0 + ty + 12 < n) C[(size_t)(row0 + ty + 12) * 64 + tx] = acc3;
}

// ---- agg init with self-loop term: agg[i][:] = h[i][:] * dinv[i]^2 -------
__global__ __launch_bounds__(THREADS) void k_init_self(
    const float* __restrict__ h, const float* __restrict__ dinv,
    float* __restrict__ agg, int n) {
  int t = blockIdx.x * blockDim.x + threadIdx.x;   // n*16 threads (float4)
  int i = t >> 4;
  if (i >= n) return;
  float s = dinv[i];
  s = s * s;
  float4 v = ((const float4*)h)[t];
  v.x *= s; v.y *= s; v.z *= s; v.w *= s;
  ((float4*)agg)[t] = v;
}

// ---- edge scatter: agg[dst] += h[src] * dinv[src]*dinv[dst] --------------
// 16 lanes per edge; each lane gathers one float4 and does 4 atomicAdds.
__global__ __launch_bounds__(THREADS) void k_scatter(
    const float* __restrict__ h, const float* __restrict__ dinv,
    const int* __restrict__ src, const int* __restrict__ dst,
    float* __restrict__ agg, int E) {
  int t = blockIdx.x * blockDim.x + threadIdx.x;
  int e = t >> 4, c = t & 15;
  if (e >= E) return;
  int s = src[e], d = dst[e];
  float nrm = dinv[s] * dinv[d];
  float4 v = ((const float4*)h)[(size_t)s * 16 + c];
  float* out = agg + (size_t)d * 64 + c * 4;
  atomicAdd(out + 0, v.x * nrm);
  atomicAdd(out + 1, v.y * nrm);
  atomicAdd(out + 2, v.z * nrm);
  atomicAdd(out + 3, v.w * nrm);
}

// ---- finalize: out[i][j] = relu(agg[i][j] + b[j]) ------------------------
__global__ __launch_bounds__(THREADS) void k_fin_relu(
    const float* __restrict__ agg, const float* __restrict__ b,
    float* __restrict__ out, int n) {
  int t = blockIdx.x * blockDim.x + threadIdx.x;   // n*16 threads (float4)
  int i = t >> 4;
  if (i >= n) return;
  float4 v = ((const float4*)agg)[t];
  float4 bb = ((const float4*)b)[t & 15];
  v.x = fmaxf(v.x + bb.x, 0.f);
  v.y = fmaxf(v.y + bb.y, 0.f);
  v.z = fmaxf(v.z + bb.z, 0.f);
  v.w = fmaxf(v.w + bb.w, 0.f);
  ((float4*)out)[t] = v;
}

// ---- layer 3: h3[i] = a2[i,:]@W3 ; out[i] = h3[i]*dinv[i]^2 + b3 ---------
__global__ __launch_bounds__(THREADS) void k_gemv_init(
    const float* __restrict__ a2, const float* __restrict__ W3,
    const float* __restrict__ dinv, const float* __restrict__ b3,
    float* __restrict__ h3, float* __restrict__ out, int n) {
  int t = blockIdx.x * blockDim.x + threadIdx.x;
  int i = t >> 4, p = t & 15;
  if (i >= n) return;
  float4 v = ((const float4*)a2)[t];
  float4 w = ((const float4*)W3)[p];
  float sum = v.x * w.x + v.y * w.y + v.z * w.z + v.w * w.w;
  sum += __shfl_down(sum, 8, 16);
  sum += __shfl_down(sum, 4, 16);
  sum += __shfl_down(sum, 2, 16);
  sum += __shfl_down(sum, 1, 16);
  if (p == 0) {
    h3[i] = sum;
    float di = dinv[i];
    out[i] = sum * di * di + b3[0];
  }
}

__global__ __launch_bounds__(THREADS) void k_scatter1(
    const float* __restrict__ h3, const float* __restrict__ dinv,
    const int* __restrict__ src, const int* __restrict__ dst,
    float* __restrict__ out, int E) {
  int e = blockIdx.x * blockDim.x + threadIdx.x;
  if (e >= E) return;
  int s = src[e], d = dst[e];
  atomicAdd(&out[d], h3[s] * dinv[s] * dinv[d]);
}

extern "C" void kernel_launch(void* const* d_in, const int* in_sizes, int n_in,
                              void* d_out, int out_size, void* d_ws, size_t ws_size,
                              hipStream_t stream) {
  const float* x  = (const float*)d_in[0];
  const int*   ei = (const int*)d_in[1];
  const float* W1 = (const float*)d_in[2];
  const float* b1 = (const float*)d_in[3];
  const float* W2 = (const float*)d_in[4];
  const float* b2 = (const float*)d_in[5];
  const float* W3 = (const float*)d_in[6];
  const float* b3 = (const float*)d_in[7];
  float* out = (float*)d_out;

  const int n = in_sizes[0] / 64;    // 100000
  const int E = in_sizes[1] / 2;     // 1600000
  const int* src = ei;
  const int* dst = ei + E;

  float* dinv = (float*)d_ws;                       // n
  float* h3   = dinv + n;                           // n
  float* bufA = h3 + n;                             // n*64
  float* bufB = bufA + (size_t)n * 64;              // n*64

  const int gN   = (n + THREADS - 1) / THREADS;
  const int gE   = (E + THREADS - 1) / THREADS;
  const int gN16 = ((size_t)n * 16 + THREADS - 1) / THREADS;
  const int gE16 = ((size_t)E * 16 + THREADS - 1) / THREADS;
  const int gRows = (n + 15) / 16;

  // degree -> dinv (shared by all layers)
  hipMemsetAsync(dinv, 0, (size_t)n * sizeof(float), stream);
  k_count_deg<<<gE, THREADS, 0, stream>>>(dst, dinv, E);
  k_make_dinv<<<gN, THREADS, 0, stream>>>(dinv, n);

  // layer 1: h1 = x@W1 -> bufA; agg -> bufB; a1 = relu(agg+b1) -> bufA
  k_gemm64<<<gRows, THREADS, 0, stream>>>(x, W1, bufA, n);
  k_init_self<<<gN16, THREADS, 0, stream>>>(bufA, dinv, bufB, n);
  k_scatter<<<gE16, THREADS, 0, stream>>>(bufA, dinv, src, dst, bufB, E);
  k_fin_relu<<<gN16, THREADS, 0, stream>>>(bufB, b1, bufA, n);

  // layer 2: h2 = a1@W2 -> bufB; agg -> bufA; a2 = relu(agg+b2) -> bufB
  k_gemm64<<<gRows, THREADS, 0, stream>>>(bufA, W2, bufB, n);
  k_init_self<<<gN16, THREADS, 0, stream>>>(bufB, dinv, bufA, n);
  k_scatter<<<gE16, THREADS, 0, stream>>>(bufB, dinv, src, dst, bufA, E);
  k_fin_relu<<<gN16, THREADS, 0, stream>>>(bufA, b2, bufB, n);

  // layer 3: h3 = a2@W3; out = h3*dinv^2 + b3 + scatter
  k_gemv_init<<<gN16, THREADS, 0, stream>>>(bufB, W3, dinv, b3, h3, out, n);
  k_scatter1<<<gE, THREADS, 0, stream>>>(h3, dinv, src, dst, out, E);
}

// Round 2
// 768.049 us; speedup vs baseline: 3.9561x; 3.9561x over previous
//
#include <hip/hip_runtime.h>

// GCN 3-layer forward: N=100000 nodes, E=1600000 edges, D=64.
// Strategy: build CSR-by-dst once (count -> scan -> fill with packed
// (src, norm) per edge), then each layer is dense GEMM + gather-only
// aggregation (one wave per node, lane = column). No fp32 atomics.

#define THREADS 256
#define SCAN_T 1024

// ---- degree count (int atomics, cheap) -----------------------------------
__global__ __launch_bounds__(THREADS) void k_count(
    const int* __restrict__ dst, int* __restrict__ cnt, int E) {
  int e = blockIdx.x * blockDim.x + threadIdx.x;
  if (e < E) atomicAdd(&cnt[dst[e]], 1);
}

// ---- single-workgroup exclusive scan + dinv ------------------------------
__global__ __launch_bounds__(SCAN_T) void k_scan(
    const int* __restrict__ cnt, int* __restrict__ rowptr,
    int* __restrict__ cursor, float* __restrict__ dinv, int n) {
  __shared__ int sums[SCAN_T];
  int t = threadIdx.x;
  int chunk = (n + SCAN_T - 1) / SCAN_T;
  int lo = t * chunk, hi = min(lo + chunk, n);
  if (lo > n) lo = n;
  if (hi < lo) hi = lo;
  int s = 0;
  for (int i = lo; i < hi; i++) s += cnt[i];
  sums[t] = s;
  __syncthreads();
  // Hillis-Steele inclusive scan
  for (int off = 1; off < SCAN_T; off <<= 1) {
    int v = (t >= off) ? sums[t - off] : 0;
    __syncthreads();
    sums[t] += v;
    __syncthreads();
  }
  int base = (t == 0) ? 0 : sums[t - 1];
  for (int i = lo; i < hi; i++) {
    rowptr[i] = base;
    cursor[i] = base;
    int c = cnt[i];
    dinv[i] = rsqrtf((float)c + 1.0f);
    base += c;
  }
  if (t == SCAN_T - 1) rowptr[n] = base;  // == E
}

// ---- fill CSR: es2[p] = (src, norm) --------------------------------------
__global__ __launch_bounds__(THREADS) void k_fill(
    const int* __restrict__ src, const int* __restrict__ dst,
    const float* __restrict__ dinv, int* __restrict__ cursor,
    int2* __restrict__ es2, int E) {
  int e = blockIdx.x * blockDim.x + threadIdx.x;
  if (e >= E) return;
  int s = src[e], d = dst[e];
  int p = atomicAdd(&cursor[d], 1);
  float w = dinv[s] * dinv[d];
  es2[p] = make_int2(s, __float_as_int(w));
}

// ---- dense GEMM: C[n,64] = A[n,64] @ W[64,64] ----------------------------
__global__ __launch_bounds__(THREADS) void k_gemm64(
    const float* __restrict__ A, const float* __restrict__ W,
    float* __restrict__ C, int n) {
  __shared__ float Ws[64][64];
  __shared__ float As[16][64];
  int t = threadIdx.x;
  const float4* W4 = (const float4*)W;
  float4* Ws4 = (float4*)&Ws[0][0];
#pragma unroll
  for (int i = 0; i < 4; i++) Ws4[t + i * 256] = W4[t + i * 256];

  int row0 = blockIdx.x * 16;
  const float4* A4 = (const float4*)(A + (size_t)row0 * 64);
  float4* As4 = (float4*)&As[0][0];
  if (row0 + 16 <= n) {
    As4[t] = A4[t];
  } else {
    int elem = t * 4;
    if (row0 * 64 + elem < n * 64) As4[t] = A4[t];
  }
  __syncthreads();

  int tx = t & 63, ty = t >> 6;
  float acc0 = 0.f, acc1 = 0.f, acc2 = 0.f, acc3 = 0.f;
#pragma unroll
  for (int k = 0; k < 64; k++) {
    float w = Ws[k][tx];
    acc0 = fmaf(As[ty][k],      w, acc0);
    acc1 = fmaf(As[ty + 4][k],  w, acc1);
    acc2 = fmaf(As[ty + 8][k],  w, acc2);
    acc3 = fmaf(As[ty + 12][k], w, acc3);
  }
  if (row0 + ty      < n) C[(size_t)(row0 + ty)      * 64 + tx] = acc0;
  if (row0 + ty + 4  < n) C[(size_t)(row0 + ty + 4)  * 64 + tx] = acc1;
  if (row0 + ty + 8  < n) C[(size_t)(row0 + ty + 8)  * 64 + tx] = acc2;
  if (row0 + ty + 12 < n) C[(size_t)(row0 + ty + 12) * 64 + tx] = acc3;
}

// ---- gather aggregation: one wave per node, lane = column ----------------
// out[i][j] = relu( sum_p h[es2[p].s][j]*es2[p].w + h[i][j]*dinv[i]^2 + b[j] )
template <int RELU>
__global__ __launch_bounds__(THREADS) void k_agg64(
    const float* __restrict__ h, const float* __restrict__ dinv,
    const int* __restrict__ rowptr, const int2* __restrict__ es2,
    const float* __restrict__ b, float* __restrict__ out, int n) {
  int i = (blockIdx.x * THREADS + threadIdx.x) >> 6;  // node = global wave id
  if (i >= n) return;
  int lane = threadIdx.x & 63;
  int p = rowptr[i], p1 = rowptr[i + 1];
  float acc = 0.f, acc2 = 0.f;
  for (; p + 1 < p1; p += 2) {
    int2 a = es2[p];
    int2 c = es2[p + 1];
    acc  = fmaf(h[(size_t)a.x * 64 + lane], __int_as_float(a.y), acc);
    acc2 = fmaf(h[(size_t)c.x * 64 + lane], __int_as_float(c.y), acc2);
  }
  if (p < p1) {
    int2 a = es2[p];
    acc = fmaf(h[(size_t)a.x * 64 + lane], __int_as_float(a.y), acc);
  }
  acc += acc2;
  float di = dinv[i];
  acc = fmaf(h[(size_t)i * 64 + lane], di * di, acc);
  acc += b[lane];
  if (RELU) acc = fmaxf(acc, 0.f);
  out[(size_t)i * 64 + lane] = acc;
}

// ---- layer 3: h3[i] = a2[i,:] @ W3 ---------------------------------------
__global__ __launch_bounds__(THREADS) void k_gemv(
    const float* __restrict__ a2, const float* __restrict__ W3,
    float* __restrict__ h3, int n) {
  int t = blockIdx.x * blockDim.x + threadIdx.x;
  int i = t >> 4, p = t & 15;
  if (i >= n) return;
  float4 v = ((const float4*)a2)[t];
  float4 w = ((const float4*)W3)[p];
  float sum = v.x * w.x + v.y * w.y + v.z * w.z + v.w * w.w;
  sum += __shfl_down(sum, 8, 16);
  sum += __shfl_down(sum, 4, 16);
  sum += __shfl_down(sum, 2, 16);
  sum += __shfl_down(sum, 1, 16);
  if (p == 0) h3[i] = sum;
}

// ---- layer-3 aggregation: thread per node (scalar) -----------------------
__global__ __launch_bounds__(THREADS) void k_agg1(
    const float* __restrict__ h3, const float* __restrict__ dinv,
    const int* __restrict__ rowptr, const int2* __restrict__ es2,
    const float* __restrict__ b3, float* __restrict__ out, int n) {
  int i = blockIdx.x * blockDim.x + threadIdx.x;
  if (i >= n) return;
  int p = rowptr[i], p1 = rowptr[i + 1];
  float acc = 0.f;
  for (; p < p1; p++) {
    int2 a = es2[p];
    acc = fmaf(h3[a.x], __int_as_float(a.y), acc);
  }
  float di = dinv[i];
  out[i] = acc + h3[i] * di * di + b3[0];
}

extern "C" void kernel_launch(void* const* d_in, const int* in_sizes, int n_in,
                              void* d_out, int out_size, void* d_ws, size_t ws_size,
                              hipStream_t stream) {
  const float* x  = (const float*)d_in[0];
  const int*   ei = (const int*)d_in[1];
  const float* W1 = (const float*)d_in[2];
  const float* b1 = (const float*)d_in[3];
  const float* W2 = (const float*)d_in[4];
  const float* b2 = (const float*)d_in[5];
  const float* W3 = (const float*)d_in[6];
  const float* b3 = (const float*)d_in[7];
  float* out = (float*)d_out;

  const int n = in_sizes[0] / 64;    // 100000
  const int E = in_sizes[1] / 2;     // 1600000
  const int* src = ei;
  const int* dst = ei + E;

  // workspace layout (all offsets keep 8B alignment)
  int*   cnt    = (int*)d_ws;                       // n
  int*   rowptr = cnt + n;                          // n+1
  int*   cursor = rowptr + n + 1;                   // n+1  (3n+2 ints, even)
  int2*  es2    = (int2*)(cursor + n + 1);          // E int2 (8B each)
  float* dinv   = (float*)(es2 + E);                // n
  float* h3     = dinv + n;                         // n
  float* bufA   = h3 + n;                           // n*64
  float* bufB   = bufA + (size_t)n * 64;            // n*64

  const int gE    = (E + THREADS - 1) / THREADS;
  const int gN    = (n + THREADS - 1) / THREADS;
  const int gN16  = ((n * 16) + THREADS - 1) / THREADS;
  const int gRows = (n + 15) / 16;
  const int gWave = (n + 3) / 4;      // 4 waves (nodes) per block

  // CSR build (shared by all 3 layers)
  hipMemsetAsync(cnt, 0, (size_t)n * sizeof(int), stream);
  k_count<<<gE, THREADS, 0, stream>>>(dst, cnt, E);
  k_scan<<<1, SCAN_T, 0, stream>>>(cnt, rowptr, cursor, dinv, n);
  k_fill<<<gE, THREADS, 0, stream>>>(src, dst, dinv, cursor, es2, E);

  // layer 1
  k_gemm64<<<gRows, THREADS, 0, stream>>>(x, W1, bufA, n);
  k_agg64<1><<<gWave, THREADS, 0, stream>>>(bufA, dinv, rowptr, es2, b1, bufB, n);
  // layer 2
  k_gemm64<<<gRows, THREADS, 0, stream>>>(bufB, W2, bufA, n);
  k_agg64<1><<<gWave, THREADS, 0, stream>>>(bufA, dinv, rowptr, es2, b2, bufB, n);
  // layer 3
  k_gemv<<<gN16, THREADS, 0, stream>>>(bufB, W3, h3, n);
  k_agg1<<<gN, THREADS, 0, stream>>>(h3, dinv, rowptr, es2, b3, out, n);
}

// Round 4
// 519.425 us; speedup vs baseline: 5.8497x; 1.4787x over previous
//
#include <hip/hip_runtime.h>

// GCN 3-layer forward: N=100000 nodes, E=1600000 edges, D=64.
// CSR-by-dst build (count -> hierarchical scan -> fill with packed (src,norm))
// then per layer: dense GEMM + gather-only aggregation (wave per node).
// Round 4: fix round-3 ping-pong bug (layer-2 GEMM must read the layer-1
// aggregation output bufB, not the raw GEMM output bufA). Scan unchanged.

#define THREADS 256
#define SCAN_ITEMS 1024   // cnt elements per scan block (256 threads x int4)

// ---- degree count (int atomics) ------------------------------------------
__global__ __launch_bounds__(THREADS) void k_count(
    const int* __restrict__ dst, int* __restrict__ cnt, int E) {
  int e = blockIdx.x * blockDim.x + threadIdx.x;
  if (e < E) atomicAdd(&cnt[dst[e]], 1);
}

// ---- scan pass 1: per-block partial sums ---------------------------------
__global__ __launch_bounds__(THREADS) void k_partial(
    const int* __restrict__ cnt, int* __restrict__ partial, int n) {
  int t = threadIdx.x;
  int base = blockIdx.x * SCAN_ITEMS + t * 4;
  int4 c = make_int4(0, 0, 0, 0);
  if (base + 3 < n) c = *(const int4*)(cnt + base);
  else {
    if (base + 0 < n) c.x = cnt[base + 0];
    if (base + 1 < n) c.y = cnt[base + 1];
    if (base + 2 < n) c.z = cnt[base + 2];
  }
  int s = c.x + c.y + c.z + c.w;
#pragma unroll
  for (int off = 32; off >= 1; off >>= 1) s += __shfl_xor(s, off, 64);
  __shared__ int ws[4];
  int lane = t & 63, wid = t >> 6;
  if (lane == 0) ws[wid] = s;
  __syncthreads();
  if (t == 0) partial[blockIdx.x] = ws[0] + ws[1] + ws[2] + ws[3];
}

// ---- scan pass 2: scan the partials (single small block) -----------------
__global__ __launch_bounds__(THREADS) void k_scan_partial(
    const int* __restrict__ partial, int* __restrict__ partial_scan,
    int nb, int* __restrict__ rowptr, int n, int E) {
  __shared__ int sh[THREADS];
  int t = threadIdx.x;
  int v = (t < nb) ? partial[t] : 0;
  sh[t] = v;
  __syncthreads();
  for (int off = 1; off < THREADS; off <<= 1) {
    int u = (t >= off) ? sh[t - off] : 0;
    __syncthreads();
    sh[t] += u;
    __syncthreads();
  }
  if (t < nb) partial_scan[t] = sh[t] - v;   // exclusive
  if (t == 0) rowptr[n] = E;
}

// ---- scan pass 3: in-block exclusive scan + write rowptr/cursor/dinv -----
__global__ __launch_bounds__(THREADS) void k_scan_blocks(
    const int* __restrict__ cnt, const int* __restrict__ partial_scan,
    int* __restrict__ rowptr, int* __restrict__ cursor,
    float* __restrict__ dinv, int n) {
  int t = threadIdx.x;
  int base = blockIdx.x * SCAN_ITEMS + t * 4;
  int4 c = make_int4(0, 0, 0, 0);
  if (base + 3 < n) c = *(const int4*)(cnt + base);
  else {
    if (base + 0 < n) c.x = cnt[base + 0];
    if (base + 1 < n) c.y = cnt[base + 1];
    if (base + 2 < n) c.z = cnt[base + 2];
  }
  int s = c.x + c.y + c.z + c.w;
  int lane = t & 63, wid = t >> 6;
  int v = s;
#pragma unroll
  for (int off = 1; off < 64; off <<= 1) {
    int u = __shfl_up(v, off, 64);
    if (lane >= off) v += u;
  }
  __shared__ int wsum[4];
  if (lane == 63) wsum[wid] = v;
  __syncthreads();
  int woff = 0;
  for (int w = 0; w < wid; w++) woff += wsum[w];
  int ex = (v - s) + woff + partial_scan[blockIdx.x];  // exclusive prefix
  int e0 = ex, e1 = e0 + c.x, e2 = e1 + c.y, e3 = e2 + c.z;
  if (base + 0 < n) { rowptr[base + 0] = e0; cursor[base + 0] = e0; dinv[base + 0] = rsqrtf((float)c.x + 1.f); }
  if (base + 1 < n) { rowptr[base + 1] = e1; cursor[base + 1] = e1; dinv[base + 1] = rsqrtf((float)c.y + 1.f); }
  if (base + 2 < n) { rowptr[base + 2] = e2; cursor[base + 2] = e2; dinv[base + 2] = rsqrtf((float)c.z + 1.f); }
  if (base + 3 < n) { rowptr[base + 3] = e3; cursor[base + 3] = e3; dinv[base + 3] = rsqrtf((float)c.w + 1.f); }
}

// ---- fill CSR: es2[p] = (src, norm) --------------------------------------
__global__ __launch_bounds__(THREADS) void k_fill(
    const int* __restrict__ src, const int* __restrict__ dst,
    const float* __restrict__ dinv, int* __restrict__ cursor,
    int2* __restrict__ es2, int E) {
  int e = blockIdx.x * blockDim.x + threadIdx.x;
  if (e >= E) return;
  int s = src[e], d = dst[e];
  int p = atomicAdd(&cursor[d], 1);
  float w = dinv[s] * dinv[d];
  es2[p] = make_int2(s, __float_as_int(w));
}

// ---- dense GEMM: C[n,64] = A[n,64] @ W[64,64] ----------------------------
__global__ __launch_bounds__(THREADS) void k_gemm64(
    const float* __restrict__ A, const float* __restrict__ W,
    float* __restrict__ C, int n) {
  __shared__ float Ws[64][64];
  __shared__ float As[16][64];
  int t = threadIdx.x;
  const float4* W4 = (const float4*)W;
  float4* Ws4 = (float4*)&Ws[0][0];
#pragma unroll
  for (int i = 0; i < 4; i++) Ws4[t + i * 256] = W4[t + i * 256];

  int row0 = blockIdx.x * 16;
  const float4* A4 = (const float4*)(A + (size_t)row0 * 64);
  float4* As4 = (float4*)&As[0][0];
  if (row0 + 16 <= n) {
    As4[t] = A4[t];
  } else {
    int elem = t * 4;
    if (row0 * 64 + elem < n * 64) As4[t] = A4[t];
  }
  __syncthreads();

  int tx = t & 63, ty = t >> 6;
  float acc0 = 0.f, acc1 = 0.f, acc2 = 0.f, acc3 = 0.f;
#pragma unroll
  for (int k = 0; k < 64; k++) {
    float w = Ws[k][tx];
    acc0 = fmaf(As[ty][k],      w, acc0);
    acc1 = fmaf(As[ty + 4][k],  w, acc1);
    acc2 = fmaf(As[ty + 8][k],  w, acc2);
    acc3 = fmaf(As[ty + 12][k], w, acc3);
  }
  if (row0 + ty      < n) C[(size_t)(row0 + ty)      * 64 + tx] = acc0;
  if (row0 + ty + 4  < n) C[(size_t)(row0 + ty + 4)  * 64 + tx] = acc1;
  if (row0 + ty + 8  < n) C[(size_t)(row0 + ty + 8)  * 64 + tx] = acc2;
  if (row0 + ty + 12 < n) C[(size_t)(row0 + ty + 12) * 64 + tx] = acc3;
}

// ---- gather aggregation: one wave per node, lane = column ----------------
template <int RELU>
__global__ __launch_bounds__(THREADS) void k_agg64(
    const float* __restrict__ h, const float* __restrict__ dinv,
    const int* __restrict__ rowptr, const int2* __restrict__ es2,
    const float* __restrict__ b, float* __restrict__ out, int n) {
  int i = (blockIdx.x * THREADS + threadIdx.x) >> 6;
  if (i >= n) return;
  int lane = threadIdx.x & 63;
  int p = rowptr[i], p1 = rowptr[i + 1];
  float acc = 0.f, acc2 = 0.f;
  for (; p + 1 < p1; p += 2) {
    int2 a = es2[p];
    int2 c = es2[p + 1];
    acc  = fmaf(h[(size_t)a.x * 64 + lane], __int_as_float(a.y), acc);
    acc2 = fmaf(h[(size_t)c.x * 64 + lane], __int_as_float(c.y), acc2);
  }
  if (p < p1) {
    int2 a = es2[p];
    acc = fmaf(h[(size_t)a.x * 64 + lane], __int_as_float(a.y), acc);
  }
  acc += acc2;
  float di = dinv[i];
  acc = fmaf(h[(size_t)i * 64 + lane], di * di, acc);
  acc += b[lane];
  if (RELU) acc = fmaxf(acc, 0.f);
  out[(size_t)i * 64 + lane] = acc;
}

// ---- layer 3: h3[i] = a2[i,:] @ W3 ---------------------------------------
__global__ __launch_bounds__(THREADS) void k_gemv(
    const float* __restrict__ a2, const float* __restrict__ W3,
    float* __restrict__ h3, int n) {
  int t = blockIdx.x * blockDim.x + threadIdx.x;
  int i = t >> 4, p = t & 15;
  if (i >= n) return;
  float4 v = ((const float4*)a2)[t];
  float4 w = ((const float4*)W3)[p];
  float sum = v.x * w.x + v.y * w.y + v.z * w.z + v.w * w.w;
  sum += __shfl_down(sum, 8, 16);
  sum += __shfl_down(sum, 4, 16);
  sum += __shfl_down(sum, 2, 16);
  sum += __shfl_down(sum, 1, 16);
  if (p == 0) h3[i] = sum;
}

// ---- layer-3 aggregation: thread per node (scalar) -----------------------
__global__ __launch_bounds__(THREADS) void k_agg1(
    const float* __restrict__ h3, const float* __restrict__ dinv,
    const int* __restrict__ rowptr, const int2* __restrict__ es2,
    const float* __restrict__ b3, float* __restrict__ out, int n) {
  int i = blockIdx.x * blockDim.x + threadIdx.x;
  if (i >= n) return;
  int p = rowptr[i], p1 = rowptr[i + 1];
  float acc = 0.f;
  for (; p < p1; p++) {
    int2 a = es2[p];
    acc = fmaf(h3[a.x], __int_as_float(a.y), acc);
  }
  float di = dinv[i];
  out[i] = acc + h3[i] * di * di + b3[0];
}

extern "C" void kernel_launch(void* const* d_in, const int* in_sizes, int n_in,
                              void* d_out, int out_size, void* d_ws, size_t ws_size,
                              hipStream_t stream) {
  const float* x  = (const float*)d_in[0];
  const int*   ei = (const int*)d_in[1];
  const float* W1 = (const float*)d_in[2];
  const float* b1 = (const float*)d_in[3];
  const float* W2 = (const float*)d_in[4];
  const float* b2 = (const float*)d_in[5];
  const float* W3 = (const float*)d_in[6];
  const float* b3 = (const float*)d_in[7];
  float* out = (float*)d_out;

  const int n = in_sizes[0] / 64;    // 100000
  const int E = in_sizes[1] / 2;     // 1600000
  const int* src = ei;
  const int* dst = ei + E;
  const int NB = (n + SCAN_ITEMS - 1) / SCAN_ITEMS;   // 98 (fits in THREADS)

  // workspace layout (8B alignment maintained)
  int*   cnt     = (int*)d_ws;                        // n
  int*   rowptr  = cnt + n;                           // n+1
  int*   cursor  = rowptr + n + 1;                    // n+1
  int*   partial = cursor + n + 1;                    // THREADS
  int*   pscan   = partial + THREADS;                 // THREADS  (3n+2+512 ints, even)
  int2*  es2     = (int2*)(pscan + THREADS);          // E int2
  float* dinv    = (float*)(es2 + E);                 // n
  float* h3      = dinv + n;                          // n
  float* bufA    = h3 + n;                            // n*64
  float* bufB    = bufA + (size_t)n * 64;             // n*64

  const int gE    = (E + THREADS - 1) / THREADS;
  const int gN    = (n + THREADS - 1) / THREADS;
  const int gN16  = ((n * 16) + THREADS - 1) / THREADS;
  const int gRows = (n + 15) / 16;
  const int gWave = (n + 3) / 4;

  // CSR build (shared by all 3 layers)
  hipMemsetAsync(cnt, 0, (size_t)n * sizeof(int), stream);
  k_count<<<gE, THREADS, 0, stream>>>(dst, cnt, E);
  k_partial<<<NB, THREADS, 0, stream>>>(cnt, partial, n);
  k_scan_partial<<<1, THREADS, 0, stream>>>(partial, pscan, NB, rowptr, n, E);
  k_scan_blocks<<<NB, THREADS, 0, stream>>>(cnt, pscan, rowptr, cursor, dinv, n);
  k_fill<<<gE, THREADS, 0, stream>>>(src, dst, dinv, cursor, es2, E);

  // layer 1: h1 = x@W1 -> bufA; a1 = agg(h1) -> bufB
  k_gemm64<<<gRows, THREADS, 0, stream>>>(x, W1, bufA, n);
  k_agg64<1><<<gWave, THREADS, 0, stream>>>(bufA, dinv, rowptr, es2, b1, bufB, n);
  // layer 2: h2 = a1@W2 -> bufA; a2 = agg(h2) -> bufB
  k_gemm64<<<gRows, THREADS, 0, stream>>>(bufB, W2, bufA, n);
  k_agg64<1><<<gWave, THREADS, 0, stream>>>(bufA, dinv, rowptr, es2, b2, bufB, n);
  // layer 3: h3 = a2@W3; out = agg(h3) + b3
  k_gemv<<<gN16, THREADS, 0, stream>>>(bufB, W3, h3, n);
  k_agg1<<<gN, THREADS, 0, stream>>>(h3, dinv, rowptr, es2, b3, out, n);
}

// Round 5
// 472.221 us; speedup vs baseline: 6.4344x; 1.1000x over previous
//
#include <hip/hip_runtime.h>

// GCN 3-layer forward: N=100000 nodes, E=1600000 edges, D=64.
// CSR-by-dst build (count -> hierarchical scan -> fill src-only edge array),
// per layer: dense GEMM with dinv-row-scale epilogue + gather-only
// aggregation (4 edges per wave, float4 lanes, butterfly combine).
// Round 5: agg revamp for memory-level parallelism; src-only edge array.

#define THREADS 256
#define SCAN_ITEMS 1024   // cnt elements per scan block (256 threads x int4)

// ---- degree count (int atomics) ------------------------------------------
__global__ __launch_bounds__(THREADS) void k_count(
    const int* __restrict__ dst, int* __restrict__ cnt, int E) {
  int e = blockIdx.x * blockDim.x + threadIdx.x;
  if (e < E) atomicAdd(&cnt[dst[e]], 1);
}

// ---- scan pass 1: per-block partial sums ---------------------------------
__global__ __launch_bounds__(THREADS) void k_partial(
    const int* __restrict__ cnt, int* __restrict__ partial, int n) {
  int t = threadIdx.x;
  int base = blockIdx.x * SCAN_ITEMS + t * 4;
  int4 c = make_int4(0, 0, 0, 0);
  if (base + 3 < n) c = *(const int4*)(cnt + base);
  else {
    if (base + 0 < n) c.x = cnt[base + 0];
    if (base + 1 < n) c.y = cnt[base + 1];
    if (base + 2 < n) c.z = cnt[base + 2];
  }
  int s = c.x + c.y + c.z + c.w;
#pragma unroll
  for (int off = 32; off >= 1; off >>= 1) s += __shfl_xor(s, off, 64);
  __shared__ int ws[4];
  int lane = t & 63, wid = t >> 6;
  if (lane == 0) ws[wid] = s;
  __syncthreads();
  if (t == 0) partial[blockIdx.x] = ws[0] + ws[1] + ws[2] + ws[3];
}

// ---- scan pass 2: scan the partials (single small block) -----------------
__global__ __launch_bounds__(THREADS) void k_scan_partial(
    const int* __restrict__ partial, int* __restrict__ partial_scan,
    int nb, int* __restrict__ rowptr, int n, int E) {
  __shared__ int sh[THREADS];
  int t = threadIdx.x;
  int v = (t < nb) ? partial[t] : 0;
  sh[t] = v;
  __syncthreads();
  for (int off = 1; off < THREADS; off <<= 1) {
    int u = (t >= off) ? sh[t - off] : 0;
    __syncthreads();
    sh[t] += u;
    __syncthreads();
  }
  if (t < nb) partial_scan[t] = sh[t] - v;   // exclusive
  if (t == 0) rowptr[n] = E;
}

// ---- scan pass 3: in-block exclusive scan + write rowptr/cursor/dinv -----
__global__ __launch_bounds__(THREADS) void k_scan_blocks(
    const int* __restrict__ cnt, const int* __restrict__ partial_scan,
    int* __restrict__ rowptr, int* __restrict__ cursor,
    float* __restrict__ dinv, int n) {
  int t = threadIdx.x;
  int base = blockIdx.x * SCAN_ITEMS + t * 4;
  int4 c = make_int4(0, 0, 0, 0);
  if (base + 3 < n) c = *(const int4*)(cnt + base);
  else {
    if (base + 0 < n) c.x = cnt[base + 0];
    if (base + 1 < n) c.y = cnt[base + 1];
    if (base + 2 < n) c.z = cnt[base + 2];
  }
  int s = c.x + c.y + c.z + c.w;
  int lane = t & 63, wid = t >> 6;
  int v = s;
#pragma unroll
  for (int off = 1; off < 64; off <<= 1) {
    int u = __shfl_up(v, off, 64);
    if (lane >= off) v += u;
  }
  __shared__ int wsum[4];
  if (lane == 63) wsum[wid] = v;
  __syncthreads();
  int woff = 0;
  for (int w = 0; w < wid; w++) woff += wsum[w];
  int ex = (v - s) + woff + partial_scan[blockIdx.x];  // exclusive prefix
  int e0 = ex, e1 = e0 + c.x, e2 = e1 + c.y, e3 = e2 + c.z;
  if (base + 0 < n) { rowptr[base + 0] = e0; cursor[base + 0] = e0; dinv[base + 0] = rsqrtf((float)c.x + 1.f); }
  if (base + 1 < n) { rowptr[base + 1] = e1; cursor[base + 1] = e1; dinv[base + 1] = rsqrtf((float)c.y + 1.f); }
  if (base + 2 < n) { rowptr[base + 2] = e2; cursor[base + 2] = e2; dinv[base + 2] = rsqrtf((float)c.z + 1.f); }
  if (base + 3 < n) { rowptr[base + 3] = e3; cursor[base + 3] = e3; dinv[base + 3] = rsqrtf((float)c.w + 1.f); }
}

// ---- fill CSR: es[p] = src (norm folded into features) -------------------
__global__ __launch_bounds__(THREADS) void k_fill(
    const int* __restrict__ src, const int* __restrict__ dst,
    int* __restrict__ cursor, int* __restrict__ es, int E) {
  int e = blockIdx.x * blockDim.x + threadIdx.x;
  if (e >= E) return;
  int d = dst[e];
  int p = atomicAdd(&cursor[d], 1);
  es[p] = src[e];
}

// ---- dense GEMM + row scale: C[r,:] = (A[r,:] @ W) * dinv[r] -------------
__global__ __launch_bounds__(THREADS) void k_gemm64s(
    const float* __restrict__ A, const float* __restrict__ W,
    const float* __restrict__ dinv, float* __restrict__ C, int n) {
  __shared__ float Ws[64][64];
  __shared__ float As[16][64];
  int t = threadIdx.x;
  const float4* W4 = (const float4*)W;
  float4* Ws4 = (float4*)&Ws[0][0];
#pragma unroll
  for (int i = 0; i < 4; i++) Ws4[t + i * 256] = W4[t + i * 256];

  int row0 = blockIdx.x * 16;
  const float4* A4 = (const float4*)(A + (size_t)row0 * 64);
  float4* As4 = (float4*)&As[0][0];
  if (row0 + 16 <= n) {
    As4[t] = A4[t];
  } else {
    int elem = t * 4;
    if (row0 * 64 + elem < n * 64) As4[t] = A4[t];
  }
  __syncthreads();

  int tx = t & 63, ty = t >> 6;
  float acc0 = 0.f, acc1 = 0.f, acc2 = 0.f, acc3 = 0.f;
#pragma unroll
  for (int k = 0; k < 64; k++) {
    float w = Ws[k][tx];
    acc0 = fmaf(As[ty][k],      w, acc0);
    acc1 = fmaf(As[ty + 4][k],  w, acc1);
    acc2 = fmaf(As[ty + 8][k],  w, acc2);
    acc3 = fmaf(As[ty + 12][k], w, acc3);
  }
  if (row0 + ty      < n) C[(size_t)(row0 + ty)      * 64 + tx] = acc0 * dinv[row0 + ty];
  if (row0 + ty + 4  < n) C[(size_t)(row0 + ty + 4)  * 64 + tx] = acc1 * dinv[row0 + ty + 4];
  if (row0 + ty + 8  < n) C[(size_t)(row0 + ty + 8)  * 64 + tx] = acc2 * dinv[row0 + ty + 8];
  if (row0 + ty + 12 < n) C[(size_t)(row0 + ty + 12) * 64 + tx] = acc3 * dinv[row0 + ty + 12];
}

// ---- gather aggregation: wave per node, 4 edges x float4 lanes -----------
// hs = row-scaled features (hs[r] = h[r]*dinv[r]).
// out[i][:] = relu( dinv[i] * (sum_edges hs[src] + hs[i]) + b )
template <int RELU>
__global__ __launch_bounds__(THREADS) void k_agg64(
    const float* __restrict__ hs, const float* __restrict__ dinv,
    const int* __restrict__ rowptr, const int* __restrict__ es,
    const float* __restrict__ b, float* __restrict__ out, int n) {
  int i = (blockIdx.x * THREADS + threadIdx.x) >> 6;
  if (i >= n) return;
  int lane = threadIdx.x & 63;
  int g = lane >> 4;        // edge slot 0..3
  int c = lane & 15;        // float4 column group
  const float4* h4 = (const float4*)hs;
  int p1 = rowptr[i + 1];
  int p = rowptr[i] + g;
  float4 acc  = make_float4(0.f, 0.f, 0.f, 0.f);
  float4 acc2 = make_float4(0.f, 0.f, 0.f, 0.f);
  for (; p + 4 < p1; p += 8) {
    int s0 = es[p];
    int s1 = es[p + 4];
    float4 a0 = h4[(size_t)s0 * 16 + c];
    float4 a1 = h4[(size_t)s1 * 16 + c];
    acc.x  += a0.x; acc.y  += a0.y; acc.z  += a0.z; acc.w  += a0.w;
    acc2.x += a1.x; acc2.y += a1.y; acc2.z += a1.z; acc2.w += a1.w;
  }
  if (p < p1) {
    int s0 = es[p];
    float4 a0 = h4[(size_t)s0 * 16 + c];
    acc.x += a0.x; acc.y += a0.y; acc.z += a0.z; acc.w += a0.w;
  }
  acc.x += acc2.x; acc.y += acc2.y; acc.z += acc2.z; acc.w += acc2.w;
  // combine the 4 edge slots: lanes {c, c+16, c+32, c+48}
#pragma unroll
  for (int m = 16; m <= 32; m <<= 1) {
    acc.x += __shfl_xor(acc.x, m, 64);
    acc.y += __shfl_xor(acc.y, m, 64);
    acc.z += __shfl_xor(acc.z, m, 64);
    acc.w += __shfl_xor(acc.w, m, 64);
  }
  if (g == 0) {
    float di = dinv[i];
    float4 self = h4[(size_t)i * 16 + c];
    float4 bb = ((const float4*)b)[c];
    float4 r;
    r.x = di * (acc.x + self.x) + bb.x;
    r.y = di * (acc.y + self.y) + bb.y;
    r.z = di * (acc.z + self.z) + bb.z;
    r.w = di * (acc.w + self.w) + bb.w;
    if (RELU) {
      r.x = fmaxf(r.x, 0.f); r.y = fmaxf(r.y, 0.f);
      r.z = fmaxf(r.z, 0.f); r.w = fmaxf(r.w, 0.f);
    }
    ((float4*)out)[(size_t)i * 16 + c] = r;
  }
}

// ---- layer 3: g3[i] = (a2[i,:] @ W3) * dinv[i] ---------------------------
__global__ __launch_bounds__(THREADS) void k_gemv(
    const float* __restrict__ a2, const float* __restrict__ W3,
    const float* __restrict__ dinv, float* __restrict__ g3, int n) {
  int t = blockIdx.x * blockDim.x + threadIdx.x;
  int i = t >> 4, p = t & 15;
  if (i >= n) return;
  float4 v = ((const float4*)a2)[t];
  float4 w = ((const float4*)W3)[p];
  float sum = v.x * w.x + v.y * w.y + v.z * w.z + v.w * w.w;
  sum += __shfl_down(sum, 8, 16);
  sum += __shfl_down(sum, 4, 16);
  sum += __shfl_down(sum, 2, 16);
  sum += __shfl_down(sum, 1, 16);
  if (p == 0) g3[i] = sum * dinv[i];
}

// ---- layer-3 aggregation: thread per node --------------------------------
__global__ __launch_bounds__(THREADS) void k_agg1(
    const float* __restrict__ g3, const float* __restrict__ dinv,
    const int* __restrict__ rowptr, const int* __restrict__ es,
    const float* __restrict__ b3, float* __restrict__ out, int n) {
  int i = blockIdx.x * blockDim.x + threadIdx.x;
  if (i >= n) return;
  int p = rowptr[i], p1 = rowptr[i + 1];
  float acc = 0.f, accb = 0.f;
  for (; p + 1 < p1; p += 2) {
    acc  += g3[es[p]];
    accb += g3[es[p + 1]];
  }
  if (p < p1) acc += g3[es[p]];
  out[i] = dinv[i] * (acc + accb + g3[i]) + b3[0];
}

extern "C" void kernel_launch(void* const* d_in, const int* in_sizes, int n_in,
                              void* d_out, int out_size, void* d_ws, size_t ws_size,
                              hipStream_t stream) {
  const float* x  = (const float*)d_in[0];
  const int*   ei = (const int*)d_in[1];
  const float* W1 = (const float*)d_in[2];
  const float* b1 = (const float*)d_in[3];
  const float* W2 = (const float*)d_in[4];
  const float* b2 = (const float*)d_in[5];
  const float* W3 = (const float*)d_in[6];
  const float* b3 = (const float*)d_in[7];
  float* out = (float*)d_out;

  const int n = in_sizes[0] / 64;    // 100000
  const int E = in_sizes[1] / 2;     // 1600000
  const int* src = ei;
  const int* dst = ei + E;
  const int NB = (n + SCAN_ITEMS - 1) / SCAN_ITEMS;   // 98 (fits in THREADS)

  // workspace layout, 256B-aligned regions (float4/int4 loads everywhere)
  char* w = (char*)d_ws;
  auto alloc = [&](size_t bytes) -> void* {
    void* p = (void*)w;
    w += (bytes + 255) & ~(size_t)255;
    return p;
  };
  int*   cnt     = (int*)alloc((size_t)n * 4);
  int*   rowptr  = (int*)alloc(((size_t)n + 1) * 4);
  int*   cursor  = (int*)alloc(((size_t)n + 1) * 4);
  int*   partial = (int*)alloc((size_t)THREADS * 4);
  int*   pscan   = (int*)alloc((size_t)THREADS * 4);
  int*   es      = (int*)alloc((size_t)E * 4);
  float* dinv    = (float*)alloc((size_t)n * 4);
  float* g3      = (float*)alloc((size_t)n * 4);
  float* bufA    = (float*)alloc((size_t)n * 64 * 4);
  float* bufB    = (float*)alloc((size_t)n * 64 * 4);

  const int gE    = (E + THREADS - 1) / THREADS;
  const int gN    = (n + THREADS - 1) / THREADS;
  const int gN16  = ((n * 16) + THREADS - 1) / THREADS;
  const int gRows = (n + 15) / 16;
  const int gWave = (n + 3) / 4;

  // CSR build (shared by all 3 layers)
  hipMemsetAsync(cnt, 0, (size_t)n * sizeof(int), stream);
  k_count<<<gE, THREADS, 0, stream>>>(dst, cnt, E);
  k_partial<<<NB, THREADS, 0, stream>>>(cnt, partial, n);
  k_scan_partial<<<1, THREADS, 0, stream>>>(partial, pscan, NB, rowptr, n, E);
  k_scan_blocks<<<NB, THREADS, 0, stream>>>(cnt, pscan, rowptr, cursor, dinv, n);
  k_fill<<<gE, THREADS, 0, stream>>>(src, dst, cursor, es, E);

  // layer 1: hs1 = (x@W1)*dinv -> bufA; a1 = agg(hs1) -> bufB
  k_gemm64s<<<gRows, THREADS, 0, stream>>>(x, W1, dinv, bufA, n);
  k_agg64<1><<<gWave, THREADS, 0, stream>>>(bufA, dinv, rowptr, es, b1, bufB, n);
  // layer 2: hs2 = (a1@W2)*dinv -> bufA; a2 = agg(hs2) -> bufB
  k_gemm64s<<<gRows, THREADS, 0, stream>>>(bufB, W2, dinv, bufA, n);
  k_agg64<1><<<gWave, THREADS, 0, stream>>>(bufA, dinv, rowptr, es, b2, bufB, n);
  // layer 3: g3 = (a2@W3)*dinv; out = dinv*(agg(g3)+g3) + b3
  k_gemv<<<gN16, THREADS, 0, stream>>>(bufB, W3, dinv, g3, n);
  k_agg1<<<gN, THREADS, 0, stream>>>(g3, dinv, rowptr, es, b3, out, n);
}